// Round 2
// baseline (313.497 us; speedup 1.0000x reference)
//
#include <hip/hip_runtime.h>
#include <math.h>

// ToneStack: 3 cascaded shelf biquads over x[64, 480000] fp32.
//
// R2: exact state-composition scheme (replaces R1 warm-up):
//   k_zerostate: each (row,chunk) runs CHUNK=128 samples from zero state,
//                emits final 6-state d_k only.
//   k_matpow:    A_L = A^CHUNK (6x6 one-sample state matrix, 7 squarings).
//   k_scan:      s_k = sum_j A_L^{k-1-j} d_j, Horner-truncated at 16 terms
//                (|A_L| ~ 0.302 => 0.302^16 ~ 5e-9, covers 2048 samples).
//   k_apply:     re-run chunk from s_k, store y (same per-sample fp32 ops
//                as the reference's DF2T biquads).
// 240000 threads (~3.7 waves/SIMD) vs R1's 64000 (~0.9/SIMD) — R1 was
// latency-bound at Occupancy 9.3%, VALUBusy 35%.

constexpr int T_LEN  = 480000;
constexpr int B_ROWS = 64;
constexpr int CHUNK  = 128;             // power of 2 (7 squarings)
constexpr int KCH    = T_LEN / CHUNK;   // 3750
constexpr int NTHR   = B_ROWS * KCH;    // 240000
constexpr int MTERM  = 16;              // history terms in the state scan

struct Coeffs { float b0, b1, b2, a1, a2; };

__device__ __forceinline__ Coeffs shelf(float fc, float gdb, float Q) {
    float A  = powf(10.0f, gdb * (1.0f / 40.0f));
    float w0 = 2.0f * 3.14159265358979323846f * fc / 48000.0f;
    float sw = sinf(w0), cw = cosf(w0);
    float alpha = sw / (2.0f * Q);
    float sqA = sqrtf(A);
    float b0 = A * ((A + 1.0f) - (A - 1.0f) * cw + 2.0f * sqA * alpha);
    float b1 = 2.0f * A * ((A - 1.0f) - (A + 1.0f) * cw);
    float b2 = A * ((A + 1.0f) - (A - 1.0f) * cw - 2.0f * sqA * alpha);
    float a0 = (A + 1.0f) + (A - 1.0f) * cw + 2.0f * sqA * alpha;
    float a1 = -2.0f * ((A - 1.0f) + (A + 1.0f) * cw);
    float a2 = (A + 1.0f) + (A - 1.0f) * cw - 2.0f * sqA * alpha;
    float rr = 1.0f / a0;
    Coeffs c;
    c.b0 = b0 * rr; c.b1 = b1 * rr; c.b2 = b2 * rr;
    c.a1 = a1 * rr; c.a2 = a2 * rr;
    return c;
}

// DF2T biquad step, matches reference op-for-op:
__device__ __forceinline__ float bq(float xn, const Coeffs& c, float& z1, float& z2) {
    float y = fmaf(c.b0, xn, z1);
    z1 = fmaf(-c.a1, y, fmaf(c.b1, xn, z2));
    z2 = fmaf(c.b2, xn, -(c.a2 * y));
    return y;
}

__device__ __forceinline__ float step6(float s[6], float x,
                                       const Coeffs& c1, const Coeffs& c2, const Coeffs& c3) {
    float y1 = bq(x,  c1, s[0], s[1]);
    float y2 = bq(y1, c2, s[2], s[3]);
    float y3 = bq(y2, c3, s[4], s[5]);
    return y3;
}

// ---------------- kernel: A_L = A^CHUNK ----------------
__global__ void k_matpow(const float* __restrict__ p_lg, const float* __restrict__ p_mg,
                         const float* __restrict__ p_mf, const float* __restrict__ p_mq,
                         const float* __restrict__ p_hg, float* __restrict__ AL) {
    __shared__ float M[36], N[36];
    int t = threadIdx.x;
    Coeffs c1 = shelf(120.0f,  *p_lg, 0.707f);
    Coeffs c2 = shelf(*p_mf,   *p_mg, *p_mq);
    Coeffs c3 = shelf(4000.0f, *p_hg, 0.707f);
    if (t < 6) {
        float s[6] = {0.f,0.f,0.f,0.f,0.f,0.f};
        s[t] = 1.0f;
        step6(s, 0.0f, c1, c2, c3);      // column t of A
        #pragma unroll
        for (int i = 0; i < 6; ++i) M[i * 6 + t] = s[i];
    }
    __syncthreads();
    for (int it = 0; it < 7; ++it) {     // 2^7 = 128 = CHUNK
        float acc = 0.f;
        if (t < 36) {
            int i = t / 6, j = t % 6;
            #pragma unroll
            for (int q = 0; q < 6; ++q) acc = fmaf(M[i * 6 + q], M[q * 6 + j], acc);
        }
        __syncthreads();
        if (t < 36) M[t] = acc;
        __syncthreads();
    }
    if (t < 36) AL[t] = M[t];
}

// ---------------- kernel 1: zero-state chunk responses ----------------
__global__ __launch_bounds__(256) void k_zerostate(
    const float* __restrict__ x,
    const float* __restrict__ p_lg, const float* __restrict__ p_mg,
    const float* __restrict__ p_mf, const float* __restrict__ p_mq,
    const float* __restrict__ p_hg,
    float* __restrict__ dstates)   // SoA: dstates[i*NTHR + tid]
{
    int tid = blockIdx.x * blockDim.x + threadIdx.x;
    if (tid >= NTHR) return;
    int r = tid / KCH;
    int k = tid - r * KCH;

    Coeffs c1 = shelf(120.0f,  *p_lg, 0.707f);
    Coeffs c2 = shelf(*p_mf,   *p_mg, *p_mq);
    Coeffs c3 = shelf(4000.0f, *p_hg, 0.707f);

    const float* xr = x + (long long)r * T_LEN + (long long)k * CHUNK;
    float s[6] = {0.f,0.f,0.f,0.f,0.f,0.f};

    float4 nxt[8];
    {
        const float4* lp = (const float4*)xr;
        #pragma unroll
        for (int j = 0; j < 8; ++j) nxt[j] = lp[j];
    }
    #pragma unroll 1
    for (int blk = 0; blk < CHUNK / 32; ++blk) {
        float4 cur[8];
        #pragma unroll
        for (int j = 0; j < 8; ++j) cur[j] = nxt[j];
        if (blk + 1 < CHUNK / 32) {
            const float4* lp = (const float4*)(xr + (blk + 1) * 32);
            #pragma unroll
            for (int j = 0; j < 8; ++j) nxt[j] = lp[j];
        }
        #pragma unroll
        for (int j = 0; j < 8; ++j) {
            float4 v = cur[j];
            step6(s, v.x, c1, c2, c3);
            step6(s, v.y, c1, c2, c3);
            step6(s, v.z, c1, c2, c3);
            step6(s, v.w, c1, c2, c3);
        }
    }
    #pragma unroll
    for (int i = 0; i < 6; ++i) dstates[i * NTHR + tid] = s[i];
}

// ---------------- kernel 2: truncated Horner state scan ----------------
__global__ __launch_bounds__(256) void k_scan(
    const float* __restrict__ dstates, const float* __restrict__ AL,
    float* __restrict__ sstart)    // SoA
{
    int tid = blockIdx.x * blockDim.x + threadIdx.x;
    if (tid >= NTHR) return;
    int r = tid / KCH;
    int k = tid - r * KCH;

    float a[36];
    #pragma unroll
    for (int i = 0; i < 36; ++i) a[i] = AL[i];   // uniform -> scalar loads

    float t6[6] = {0.f,0.f,0.f,0.f,0.f,0.f};
    int m0 = k - MTERM; if (m0 < 0) m0 = 0;
    int base = r * KCH;
    for (int m = m0; m < k; ++m) {
        float dm[6];
        #pragma unroll
        for (int i = 0; i < 6; ++i) dm[i] = dstates[i * NTHR + base + m];
        float nt[6];
        #pragma unroll
        for (int i = 0; i < 6; ++i) {
            float acc = dm[i];
            #pragma unroll
            for (int j = 0; j < 6; ++j) acc = fmaf(a[i * 6 + j], t6[j], acc);
            nt[i] = acc;
        }
        #pragma unroll
        for (int i = 0; i < 6; ++i) t6[i] = nt[i];
    }
    #pragma unroll
    for (int i = 0; i < 6; ++i) sstart[i * NTHR + tid] = t6[i];
}

// ---------------- kernel 3: apply with true start states ----------------
__global__ __launch_bounds__(256) void k_apply(
    const float* __restrict__ x,
    const float* __restrict__ p_lg, const float* __restrict__ p_mg,
    const float* __restrict__ p_mf, const float* __restrict__ p_mq,
    const float* __restrict__ p_hg,
    const float* __restrict__ sstart,
    float* __restrict__ out)
{
    int tid = blockIdx.x * blockDim.x + threadIdx.x;
    if (tid >= NTHR) return;
    int r = tid / KCH;
    int k = tid - r * KCH;

    Coeffs c1 = shelf(120.0f,  *p_lg, 0.707f);
    Coeffs c2 = shelf(*p_mf,   *p_mg, *p_mq);
    Coeffs c3 = shelf(4000.0f, *p_hg, 0.707f);

    const float* xr = x   + (long long)r * T_LEN + (long long)k * CHUNK;
    float*       yr = out + (long long)r * T_LEN + (long long)k * CHUNK;

    float s[6];
    #pragma unroll
    for (int i = 0; i < 6; ++i) s[i] = sstart[i * NTHR + tid];

    float4 nxt[8];
    {
        const float4* lp = (const float4*)xr;
        #pragma unroll
        for (int j = 0; j < 8; ++j) nxt[j] = lp[j];
    }
    #pragma unroll 1
    for (int blk = 0; blk < CHUNK / 32; ++blk) {
        float4 cur[8];
        #pragma unroll
        for (int j = 0; j < 8; ++j) cur[j] = nxt[j];
        if (blk + 1 < CHUNK / 32) {
            const float4* lp = (const float4*)(xr + (blk + 1) * 32);
            #pragma unroll
            for (int j = 0; j < 8; ++j) nxt[j] = lp[j];
        }
        float4* sp = (float4*)(yr + blk * 32);
        #pragma unroll
        for (int j = 0; j < 8; ++j) {
            float4 v = cur[j];
            float4 o;
            o.x = step6(s, v.x, c1, c2, c3);
            o.y = step6(s, v.y, c1, c2, c3);
            o.z = step6(s, v.z, c1, c2, c3);
            o.w = step6(s, v.w, c1, c2, c3);
            sp[j] = o;
        }
    }
}

// ---------------- fallback: R1 warm-up kernel (if ws too small) ----------------
constexpr int F_CHUNK = 480;
constexpr int F_WARM  = 1536;
constexpr int F_KCH   = T_LEN / F_CHUNK;
constexpr int F_NTHR  = B_ROWS * F_KCH;

__global__ __launch_bounds__(256) void tonestack_fallback(
    const float* __restrict__ x,
    const float* __restrict__ p_lg, const float* __restrict__ p_mg,
    const float* __restrict__ p_mf, const float* __restrict__ p_mq,
    const float* __restrict__ p_hg,
    float* __restrict__ out)
{
    int tid = blockIdx.x * blockDim.x + threadIdx.x;
    if (tid >= F_NTHR) return;
    int r = tid / F_KCH;
    int k = tid - r * F_KCH;

    Coeffs c1 = shelf(120.0f,  *p_lg, 0.707f);
    Coeffs c2 = shelf(*p_mf,   *p_mg, *p_mq);
    Coeffs c3 = shelf(4000.0f, *p_hg, 0.707f);

    const float* xr = x   + (long long)r * T_LEN;
    float*       yr = out + (long long)r * T_LEN;

    int start = k * F_CHUNK;
    int warm  = min(start, F_WARM);
    int p0    = start - warm;
    int nblk  = (warm + F_CHUNK) >> 5;

    float s[6] = {0.f,0.f,0.f,0.f,0.f,0.f};
    float4 nxt[8];
    {
        const float4* lp = (const float4*)(xr + p0);
        #pragma unroll
        for (int j = 0; j < 8; ++j) nxt[j] = lp[j];
    }
    int pos = p0;
    #pragma unroll 1
    for (int blk = 0; blk < nblk; ++blk, pos += 32) {
        float4 cur[8];
        #pragma unroll
        for (int j = 0; j < 8; ++j) cur[j] = nxt[j];
        if (blk + 1 < nblk) {
            const float4* lp = (const float4*)(xr + pos + 32);
            #pragma unroll
            for (int j = 0; j < 8; ++j) nxt[j] = lp[j];
        }
        const bool wr = (pos >= start);
        float4* sp = (float4*)(yr + pos);
        #pragma unroll
        for (int j = 0; j < 8; ++j) {
            float4 v = cur[j];
            float4 o;
            o.x = step6(s, v.x, c1, c2, c3);
            o.y = step6(s, v.y, c1, c2, c3);
            o.z = step6(s, v.z, c1, c2, c3);
            o.w = step6(s, v.w, c1, c2, c3);
            if (wr) sp[j] = o;
        }
    }
}

extern "C" void kernel_launch(void* const* d_in, const int* in_sizes, int n_in,
                              void* d_out, int out_size, void* d_ws, size_t ws_size,
                              hipStream_t stream) {
    const float* x  = (const float*)d_in[0];
    const float* lg = (const float*)d_in[1];
    const float* mg = (const float*)d_in[2];
    const float* mf = (const float*)d_in[3];
    const float* mq = (const float*)d_in[4];
    const float* hg = (const float*)d_in[5];
    float* out = (float*)d_out;

    // workspace layout: [AL 36f | pad to 256B | dstates 6*NTHR f | sstart 6*NTHR f]
    const size_t need = 256 + 2ull * 6 * NTHR * sizeof(float);
    if (ws_size < need) {
        dim3 grid((F_NTHR + 255) / 256), block(256);
        hipLaunchKernelGGL(tonestack_fallback, grid, block, 0, stream,
                           x, lg, mg, mf, mq, hg, out);
        return;
    }

    float* AL      = (float*)d_ws;
    float* dstates = (float*)((char*)d_ws + 256);
    float* sstart  = dstates + (size_t)6 * NTHR;

    dim3 block(256);
    dim3 grid((NTHR + 255) / 256);

    hipLaunchKernelGGL(k_matpow, dim3(1), dim3(64), 0, stream, lg, mg, mf, mq, hg, AL);
    hipLaunchKernelGGL(k_zerostate, grid, block, 0, stream, x, lg, mg, mf, mq, hg, dstates);
    hipLaunchKernelGGL(k_scan, grid, block, 0, stream, dstates, AL, sstart);
    hipLaunchKernelGGL(k_apply, grid, block, 0, stream, x, lg, mg, mf, mq, hg, sstart, out);
}